// Round 17
// baseline (803.303 us; speedup 1.0000x reference)
//
#include <hip/hip_runtime.h>
#include <stdint.h>

#define TPB 256

typedef short s4v __attribute__((ext_vector_type(4)));
typedef short s8v __attribute__((ext_vector_type(8)));
typedef float f4v __attribute__((ext_vector_type(4)));

__device__ __forceinline__ unsigned short f2bf(float f) {
  union { float f; unsigned u; } v; v.f = f;
  unsigned r = v.u + 0x7FFFu + ((v.u >> 16) & 1u);
  return (unsigned short)(r >> 16);
}
__device__ __forceinline__ float bf2f(unsigned short h) {
  union { unsigned u; float f; } v; v.u = ((unsigned)h) << 16;
  return v.f;
}
__device__ __forceinline__ void gl_lds16(const void* g, void* l) {
  __builtin_amdgcn_global_load_lds(
      (const __attribute__((address_space(1))) void*)g,
      (__attribute__((address_space(3))) void*)l, 16, 0, 0);
}

// ---------------- small prep kernels ----------------

__global__ void k_cast_bf16(const float* __restrict__ src, unsigned short* __restrict__ dst, int n4) {
  int i = blockIdx.x * TPB + threadIdx.x;
  if (i >= n4) return;
  float4 v = ((const float4*)src)[i];
  ushort4 o;
  o.x = f2bf(v.x); o.y = f2bf(v.y); o.z = f2bf(v.z); o.w = f2bf(v.w);
  ((ushort4*)dst)[i] = o;
}

// wmT[dir][d][t] = w_merge[(dir*512+t)*512 + d]  (bf16). LDS-tiled transpose.
__global__ void k_prep_wmT(const float* __restrict__ wm, unsigned short* __restrict__ dst) {
  __shared__ float tile[64][65];
  const int d0 = blockIdx.x * 64, t0 = blockIdx.y * 64, dir = blockIdx.z;
  const int lo = threadIdx.x & 63, hi = threadIdx.x >> 6;
#pragma unroll
  for (int r = 0; r < 16; ++r) {
    int t = r * 4 + hi;
    tile[t][lo] = wm[(size_t)(dir * 512 + t0 + t) * 512 + d0 + lo];
  }
  __syncthreads();
#pragma unroll
  for (int r = 0; r < 16; ++r) {
    int d = r * 4 + hi;
    dst[(size_t)dir * 262144 + (size_t)(d0 + d) * 512 + t0 + lo] = f2bf(tile[lo][d]);
  }
}

// B1t[j][k]: interleaved-by-16 z/gate columns of w_in, transposed. LDS-tiled.
__global__ void k_prep_b1(const float* __restrict__ w_in, const float* __restrict__ b_in,
                          unsigned short* __restrict__ B1t, float* __restrict__ bb1) {
  __shared__ float tile[64][65];
  const int e0 = blockIdx.x * 64, k0 = blockIdx.y * 64, dir = blockIdx.z;
  const int tid = threadIdx.x;
  const int lo = tid & 63, hi = tid >> 6;
#pragma unroll
  for (int r = 0; r < 16; ++r) {
    int k = r * 4 + hi;
    tile[k][lo] = w_in[(size_t)(dir * 512 + k0 + k) * 2048 + e0 + lo];
  }
  __syncthreads();
  const int s_ = e0 >> 10;
#pragma unroll
  for (int r = 0; r < 16; ++r) {
    int e = r * 4 + hi;
    int ee = (e0 + e) & 1023;
    int g = dir * 64 + (ee >> 4);
    int j = g * 32 + s_ * 16 + (ee & 15);
    B1t[(size_t)j * 512 + k0 + lo] = f2bf(tile[lo][e]);
    if (k0 == 0 && lo == 0) bb1[j] = b_in[dir * 2048 + s_ * 1024 + ee];
  }
}

// v[dir][t] += partial over e-seg.  grid (4 dirs, 8 t-tiles, 8 e-segs); v pre-zeroed.
__global__ void k_prep_v(const float* __restrict__ lnb, const float* __restrict__ wout,
                         float* __restrict__ v) {
  const int dir = blockIdx.x, t0 = blockIdx.y * 64, e0 = blockIdx.z * 128;
  const int lt = threadIdx.x & 63, eg = threadIdx.x >> 6;
  float s = 0.f;
#pragma unroll
  for (int i = 0; i < 32; ++i) {
    int e = e0 + eg * 32 + i;
    s += lnb[dir * 1024 + e] * wout[(size_t)(dir * 1024 + e) * 512 + t0 + lt];
  }
  atomicAdd(&v[dir * 512 + t0 + lt], s);
}

// bias2[d] += partials.  grid (8 d-blocks, 16 f-segs); bias2 pre-zeroed.
__global__ void k_prep_bias2(const float* __restrict__ bmerge, const float* __restrict__ bout,
                             const float* __restrict__ v, const float* __restrict__ wmerge,
                             float* __restrict__ bias2) {
  const int d0 = blockIdx.x * 64, fs = blockIdx.y * 128;
  const int ld = threadIdx.x & 63, fg = threadIdx.x >> 6;
  float s = 0.f;
#pragma unroll
  for (int i = 0; i < 32; ++i) {
    int f = fs + fg * 32 + i;
    s += (bout[f] + v[f]) * wmerge[(size_t)f * 512 + d0 + ld];
  }
  if (blockIdx.y == 0 && fg == 0) s += bmerge[d0 + ld];
  atomicAdd(&bias2[d0 + ld], s);
}

// S[dcol*4+d] = sum_j W2p[dcol][d*1024+j]   grid 512 x 256
__global__ void k_colsum(const unsigned short* __restrict__ W2p, float* __restrict__ S) {
  const int dcol = blockIdx.x, tid = threadIdx.x;
  const unsigned short* p = W2p + (size_t)dcol * 4096 + tid * 16;
  s8v a = *(const s8v*)p, b = *(const s8v*)(p + 8);
  float s = 0.f;
#pragma unroll
  for (int j = 0; j < 8; ++j) s += bf2f((unsigned short)a[j]) + bf2f((unsigned short)b[j]);
#pragma unroll
  for (int mk = 1; mk < 64; mk <<= 1) s += __shfl_xor(s, mk);
  if ((tid & 63) == 0) S[dcol * 4 + (tid >> 6)] = s;
}

// ---------------- GEMM bodies ----------------
// ROLL body (MODE 0 / 2, K=512): 128x128 tile, BK=64, single-buffered 32 KB
// LDS, rolling K-loop. Wave tiling: 4 waves x (32 rows x full 128-N); each
// output row's full Z line from ONE wave (R15: -32%). Flattened LDS reads
// (valid since r&7 == c&7 for all fragments):
//   sw = (r<<7) + (((kk<<6)|(q<<4)) ^ ((c&7)<<4))   (R16: -6%)

template <int MODE>
__device__ __forceinline__ void gemm_roll(const unsigned short* __restrict__ A,
                                          const unsigned short* __restrict__ Bt, int K,
                                          unsigned short* __restrict__ U16out,
                                          const float* __restrict__ bb1,
                                          float* __restrict__ gsum, float* __restrict__ gsq,
                                          const float* __restrict__ lng) {
  __shared__ char lds[32768];
  const int tid = threadIdx.x;
  const int bN = blockIdx.x, bM = blockIdx.y;
  const int lane = tid & 63, wid = tid >> 6;  // wid = wave row-group (0..3)
  const int q = lane >> 4, c = lane & 15;

  const unsigned short* Bte = Bt;
  if (MODE == 2) Bte += (size_t)(bM >> 3) * (512 * 512);

  const size_t ldab = (size_t)K * 2;
  const char* Ab = (const char*)A + (size_t)bM * 128 * ldab;
  const char* Bb = (const char*)Bte + (size_t)bN * 128 * ldab;

  // Flattened LDS fragment bases.
  const int o0 = ((0 << 6) | (q << 4)) ^ ((c & 7) << 4);
  const int o1 = ((1 << 6) | (q << 4)) ^ ((c & 7) << 4);
  const char* bA0 = lds + wid * 4096 + c * 128 + o0;
  const char* bA1 = lds + wid * 4096 + c * 128 + o1;
  const char* bB0 = lds + 16384 + c * 128 + o0;
  const char* bB1 = lds + 16384 + c * 128 + o1;

  f4v acc[2][8];
  {
    f4v z = {0.f, 0.f, 0.f, 0.f};
#pragma unroll
    for (int m = 0; m < 2; ++m)
#pragma unroll
      for (int n = 0; n < 8; ++n) acc[m][n] = z;
  }

  const int NT = K >> 6;

  auto stage = [&](int kt) {
    const size_t kb = (size_t)kt << 7;
#pragma unroll
    for (int i = 0; i < 4; ++i) {
      int ci = tid + i * 256;
      int r = ci >> 3, cc = ci & 7;
      int ccs = cc ^ (r & 7);
      gl_lds16(Ab + (size_t)r * ldab + kb + ccs * 16,
               (void*)(lds + wid * 1024 + i * 4096));
    }
#pragma unroll
    for (int i = 0; i < 4; ++i) {
      int ci = tid + i * 256;
      int r = ci >> 3, cc = ci & 7;
      int ccs = cc ^ (r & 7);
      gl_lds16(Bb + (size_t)r * ldab + kb + ccs * 16,
               (void*)(lds + 16384 + wid * 1024 + i * 4096));
    }
  };

  for (int t = 0; t < NT; ++t) {
    if (t) __syncthreads();  // previous compute done reading LDS
    stage(t);
    __syncthreads();         // staged data visible (compiler drains vmcnt)

#pragma unroll
    for (int kk = 0; kk < 2; ++kk) {
      const char* pA = kk ? bA1 : bA0;
      const char* pB = kk ? bB1 : bB0;
      s8v af[2];
      af[0] = *(const s8v*)(pA);
      af[1] = *(const s8v*)(pA + 2048);
#pragma unroll
      for (int n = 0; n < 8; ++n) {
        s8v bfn = *(const s8v*)(pB + n * 2048);
        acc[0][n] = __builtin_amdgcn_mfma_f32_16x16x32_bf16(af[0], bfn, acc[0][n], 0, 0, 0);
        acc[1][n] = __builtin_amdgcn_mfma_f32_16x16x32_bf16(af[1], bfn, acc[1][n], 0, 0, 0);
      }
    }
  }

  if (MODE == 0) {
    const int dir = bN >> 4;
    float bz[4], bg[4];
#pragma unroll
    for (int p = 0; p < 4; ++p) {
      int jz = bN * 128 + p * 32 + c;
      bz[p] = bb1[jz];
      bg[p] = bb1[jz + 16];
    }
    unsigned* Zp = (unsigned*)U16out;  // u32 view, row stride 2048
#pragma unroll
    for (int m = 0; m < 2; ++m)
#pragma unroll
      for (int r = 0; r < 4; ++r) {
        int row = bM * 128 + wid * 32 + m * 16 + q * 4 + r;
        float v[4];
#pragma unroll
        for (int p = 0; p < 4; ++p) {
          float z = acc[m][2 * p][r] + bz[p];
          float g = acc[m][2 * p + 1][r] + bg[p];
          v[p] = z * (1.f / (1.f + __expf(-z))) * (1.f / (1.f + __expf(-g)));
        }
        uint2 w;
        w.x = (unsigned)f2bf(v[0]) | ((unsigned)f2bf(v[1]) << 16);
        w.y = (unsigned)f2bf(v[2]) | ((unsigned)f2bf(v[3]) << 16);
        *(uint2*)(Zp + (size_t)row * 2048 + bN * 32 + c * 2) = w;
        float a1 = v[0] + v[1] + v[2] + v[3];
        float a2 = v[0] * v[0] + v[1] * v[1] + v[2] * v[2] + v[3] * v[3];
#pragma unroll
        for (int mk = 1; mk < 16; mk <<= 1) {
          a1 += __shfl_xor(a1, mk);
          a2 += __shfl_xor(a2, mk);
        }
        if (c == 0) {
          atomicAdd(&gsum[row * 4 + dir], a1);
          atomicAdd(&gsq[row * 4 + dir], a2);
        }
      }
  }

  if (MODE == 2) {
#pragma unroll
    for (int m = 0; m < 2; ++m)
#pragma unroll
      for (int r = 0; r < 4; ++r) {
        int fl = bM * 128 + wid * 32 + m * 16 + q * 4 + r;
        float sc = lng[fl];
        int e = fl & 1023, dirf = fl >> 10;
        int g = dirf * 64 + (e >> 4);
        int fnew = (g >> 2) * 64 + (e & 15) * 4 + (g & 3);
#pragma unroll
        for (int n = 0; n < 8; ++n) {
          int d = bN * 128 + n * 16 + c;
          U16out[(size_t)d * 4096 + fnew] = f2bf(acc[m][n][r] * sc);
        }
      }
  }
}

// UNROLL body (MODE 1, K=4096): NEW 128x64 tile -> 8 bN x 128 bM = 1024
// blocks = 4 blocks/CU (was 2 — occupancy was the k_g2 limiter). Row-split
// waves (4 x 32 rows x 64 cols), acc[2][4], 24 KB LDS. Keeps the NTI=16
// full unroll + flattened bases + per-outer dir-rescale (R11 winners).
__device__ __forceinline__ void gemm_g2(const unsigned short* __restrict__ A,
                                        const unsigned short* __restrict__ Bt,
                                        float* __restrict__ F32out,
                                        const float* __restrict__ rs,
                                        const float* __restrict__ mur,
                                        const float* __restrict__ bias2,
                                        const float* __restrict__ S) {
  constexpr int K = 4096;
  __shared__ char lds[24576];
  const int tid = threadIdx.x;
  const int bN = blockIdx.x, bM = blockIdx.y;
  const int lane = tid & 63, wid = tid >> 6;
  const int q = lane >> 4, c = lane & 15;

  const size_t ldab = (size_t)K * 2;
  const char* Ab = (const char*)A + (size_t)bM * 128 * ldab;
  const char* Bb = (const char*)Bt + (size_t)bN * 64 * ldab;

  // Flattened LDS fragment bases (r&7 == c&7 identity).
  const int o0 = ((0 << 6) | (q << 4)) ^ ((c & 7) << 4);
  const int o1 = ((1 << 6) | (q << 4)) ^ ((c & 7) << 4);
  const char* bA0 = lds + wid * 4096 + c * 128 + o0;
  const char* bA1 = lds + wid * 4096 + c * 128 + o1;
  const char* bB0 = lds + 16384 + c * 128 + o0;
  const char* bB1 = lds + 16384 + c * 128 + o1;

  // Staging offsets (loop-invariant; ti*128 folds to immediates in unroll).
  size_t srcA[4], srcB[2];
  int ldsA[4], ldsB[2];
#pragma unroll
  for (int i = 0; i < 4; ++i) {
    int ci = tid + i * 256;
    int r = ci >> 3, cc = ci & 7;
    int ccs = cc ^ (r & 7);
    srcA[i] = (size_t)r * ldab + (size_t)ccs * 16;
    ldsA[i] = wid * 1024 + i * 4096;
  }
#pragma unroll
  for (int i = 0; i < 2; ++i) {
    int ci = tid + i * 256;
    int r = ci >> 3, cc = ci & 7;
    int ccs = cc ^ (r & 7);
    srcB[i] = (size_t)r * ldab + (size_t)ccs * 16;
    ldsB[i] = 16384 + wid * 1024 + i * 4096;
  }

  f4v acc[2][4];
  {
    f4v z = {0.f, 0.f, 0.f, 0.f};
#pragma unroll
    for (int m = 0; m < 2; ++m)
#pragma unroll
      for (int n = 0; n < 4; ++n) acc[m][n] = z;
  }

  float rsv[8];
#pragma unroll
  for (int i = 0; i < 8; ++i) {
    int row = bM * 128 + wid * 32 + (i >> 2) * 16 + q * 4 + (i & 3);
    rsv[i] = rs[row * 4 + 0];
  }

  const char* Ao = Ab;
  const char* Bo = Bb;
  for (int ot = 0; ot < 4; ++ot) {
    if (ot) {
      // dir boundary (outer iter == 16 K-steps): acc *= r_{d-1}/r_d
#pragma unroll
      for (int i = 0; i < 8; ++i) {
        int row = bM * 128 + wid * 32 + (i >> 2) * 16 + q * 4 + (i & 3);
        float nr = rs[row * 4 + ot];
        float f = rsv[i] / nr;
        rsv[i] = nr;
#pragma unroll
        for (int n = 0; n < 4; ++n) acc[i >> 2][n][i & 3] *= f;
      }
    }
#pragma unroll
    for (int ti = 0; ti < 16; ++ti) {
      if (ti || ot) __syncthreads();
#pragma unroll
      for (int i = 0; i < 4; ++i)
        gl_lds16(Ao + srcA[i] + (size_t)ti * 128, (void*)(lds + ldsA[i]));
#pragma unroll
      for (int i = 0; i < 2; ++i)
        gl_lds16(Bo + srcB[i] + (size_t)ti * 128, (void*)(lds + ldsB[i]));
      __syncthreads();

#pragma unroll
      for (int kk = 0; kk < 2; ++kk) {
        const char* pA = kk ? bA1 : bA0;
        const char* pB = kk ? bB1 : bB0;
        s8v af[2];
        af[0] = *(const s8v*)(pA);
        af[1] = *(const s8v*)(pA + 2048);
#pragma unroll
        for (int n = 0; n < 4; ++n) {
          s8v bfn = *(const s8v*)(pB + n * 2048);
          acc[0][n] = __builtin_amdgcn_mfma_f32_16x16x32_bf16(af[0], bfn, acc[0][n], 0, 0, 0);
          acc[1][n] = __builtin_amdgcn_mfma_f32_16x16x32_bf16(af[1], bfn, acc[1][n], 0, 0, 0);
        }
      }
    }
    Ao += (size_t)16 * 128;
    Bo += (size_t)16 * 128;
  }

  float4 S4[4];
  float bias[4];
#pragma unroll
  for (int n = 0; n < 4; ++n) {
    int col = bN * 64 + n * 16 + c;
    S4[n] = ((const float4*)S)[col];
    bias[n] = bias2[col];
  }
#pragma unroll
  for (int m = 0; m < 2; ++m)
#pragma unroll
    for (int r = 0; r < 4; ++r) {
      int row = bM * 128 + wid * 32 + m * 16 + q * 4 + r;
      float4 mu4 = ((const float4*)mur)[row];
      float rv = rsv[m * 4 + r];
#pragma unroll
      for (int n = 0; n < 4; ++n) {
        int col = bN * 64 + n * 16 + c;
        float corr = mu4.x * S4[n].x + mu4.y * S4[n].y + mu4.z * S4[n].z + mu4.w * S4[n].w;
        F32out[(size_t)row * 512 + col] = acc[m][n][r] * rv - corr + bias[n];
      }
    }
}

// Distinctly-named wrappers, all 4 blocks/CU.
__global__ __launch_bounds__(TPB, 4)
void k_g1(const unsigned short* A, const unsigned short* Bt, unsigned short* U16out,
          const float* bb1, float* gsum, float* gsq) {
  gemm_roll<0>(A, Bt, 512, U16out, bb1, gsum, gsq, nullptr);
}
__global__ __launch_bounds__(TPB, 4)
void k_g2(const unsigned short* A, const unsigned short* Bt, float* F32out,
          const float* rs, const float* mur, const float* bias2, const float* S) {
  gemm_g2(A, Bt, F32out, rs, mur, bias2, S);
}
__global__ __launch_bounds__(TPB, 4)
void k_gw(const unsigned short* A, const unsigned short* Bt, unsigned short* U16out,
          const float* lng) {
  gemm_roll<2>(A, Bt, 512, U16out, nullptr, nullptr, nullptr, lng);
}

// ---------------- post kernels ----------------

__global__ void k_stats(const float* __restrict__ gsum, const float* __restrict__ gsq,
                        float* __restrict__ rs, float* __restrict__ mur, int n) {
  int i = blockIdx.x * TPB + threadIdx.x;
  if (i >= n) return;
  float m = gsum[i] * (1.f / 1024.f);
  float v = gsq[i] * (1.f / 1024.f) - m * m;
  float r = rsqrtf(fmaxf(v, 0.f) + 1e-5f);
  rs[i] = r;
  mur[i] = m * r;
}

__global__ void k_final_ln(float* __restrict__ out, const float* __restrict__ g,
                           const float* __restrict__ b) {
  int row = blockIdx.x * 4 + (threadIdx.x >> 6);
  int lane = threadIdx.x & 63;
  float* p = out + (size_t)row * 512;
  float x[8];
  *(float4*)&x[0] = *(const float4*)(p + lane * 4);
  *(float4*)&x[4] = *(const float4*)(p + 256 + lane * 4);
  float s = 0.f;
#pragma unroll
  for (int j = 0; j < 8; ++j) s += x[j];
#pragma unroll
  for (int mk = 1; mk < 64; mk <<= 1) s += __shfl_xor(s, mk);
  float mean = s * (1.f / 512.f);
  float vs = 0.f;
#pragma unroll
  for (int j = 0; j < 8; ++j) { float d = x[j] - mean; vs += d * d; }
#pragma unroll
  for (int mk = 1; mk < 64; mk <<= 1) vs += __shfl_xor(vs, mk);
  float rstd = rsqrtf(vs * (1.f / 512.f) + 1e-5f);
  float gg[8], bb[8];
  *(float4*)&gg[0] = *(const float4*)(g + lane * 4);
  *(float4*)&gg[4] = *(const float4*)(g + 256 + lane * 4);
  *(float4*)&bb[0] = *(const float4*)(b + lane * 4);
  *(float4*)&bb[4] = *(const float4*)(b + 256 + lane * 4);
#pragma unroll
  for (int j = 0; j < 8; ++j) x[j] = (x[j] - mean) * rstd * gg[j] + bb[j];
  *(float4*)(p + lane * 4) = *(float4*)&x[0];
  *(float4*)(p + 256 + lane * 4) = *(float4*)&x[4];
}

// ---------------- launch ----------------

extern "C" void kernel_launch(void* const* d_in, const int* in_sizes, int n_in,
                              void* d_out, int out_size, void* d_ws, size_t ws_size,
                              hipStream_t stream) {
  const float* x     = (const float*)d_in[0];
  const float* w_in  = (const float*)d_in[1];
  const float* b_in  = (const float*)d_in[2];
  const float* ln_g  = (const float*)d_in[3];
  const float* ln_b  = (const float*)d_in[4];
  const float* w_out = (const float*)d_in[5];
  const float* b_out = (const float*)d_in[6];
  const float* w_mrg = (const float*)d_in[7];
  const float* b_mrg = (const float*)d_in[8];
  const float* nrm_g = (const float*)d_in[9];
  const float* nrm_b = (const float*)d_in[10];
  float* out = (float*)d_out;

  char* ws = (char*)d_ws;
  size_t off = 0;
  auto take = [&](size_t bytes) {
    char* p = ws + off;
    off += (bytes + 255) & ~(size_t)255;
    return p;
  };
  unsigned short* Xb    = (unsigned short*)take(33554432);   // x bf16 [32768][512]
  unsigned short* B1t   = (unsigned short*)take(8388608);    // w_in arranged [8192][512]
  float*          bb1   = (float*)take(32768);
  unsigned short* Wob   = (unsigned short*)take(4194304);    // w_out bf16 [4096][512]
  unsigned short* WmT   = (unsigned short*)take(2097152);    // w_merge^T bf16 [4][512][512]
  unsigned short* W2p   = (unsigned short*)take(4194304);    // combined W2' [512][4096] (F layout)
  float*          vbuf  = (float*)take(8192);
  float*          bias2 = (float*)take(2048);                // contiguous after vbuf
  float*          Sbuf  = (float*)take(8192);                // S[dcol][4]
  float*          gsum  = (float*)take(524288);
  float*          gsq   = (float*)take(524288);              // contiguous after gsum
  float*          rs    = (float*)take(524288);
  float*          mur   = (float*)take(524288);
  size_t fixed = off;

  // Largest row-chunk that fits the workspace.
  int R = 32768;
  while (R > 1024 && fixed + (size_t)R * 8192 > ws_size) R >>= 1;
  unsigned short* Zc = (unsigned short*)take((size_t)R * 8192);  // gated z chunk (F layout)

  // ---- one-time prep ----
  hipMemsetAsync(vbuf, 0, 8192 + 2048, stream);  // vbuf + bias2 (contiguous)
  k_cast_bf16<<<16384, TPB, 0, stream>>>(x, Xb, 4194304);
  k_cast_bf16<<<2048, TPB, 0, stream>>>(w_out, Wob, 524288);
  {
    dim3 g(8, 8, 4);
    k_prep_wmT<<<g, TPB, 0, stream>>>(w_mrg, WmT);
  }
  {
    dim3 g(32, 8, 4);
    k_prep_b1<<<g, TPB, 0, stream>>>(w_in, b_in, B1t, bb1);
  }
  {
    dim3 g(4, 8, 8);
    k_prep_v<<<g, TPB, 0, stream>>>(ln_b, w_out, vbuf);
  }
  {
    dim3 g(8, 16);
    k_prep_bias2<<<g, TPB, 0, stream>>>(b_mrg, b_out, vbuf, w_mrg, bias2);
  }
  {
    dim3 g(4, 32);
    k_gw<<<g, TPB, 0, stream>>>(Wob, WmT, W2p, ln_g);
  }
  k_colsum<<<512, TPB, 0, stream>>>(W2p, Sbuf);

  // ---- chunked main pipeline ----
  const int nchunks = 32768 / R;
  for (int ch = 0; ch < nchunks; ++ch) {
    const size_t m0 = (size_t)ch * R;
    const int nbM = R / 128;
    // Zero the FULL gsum+gsq allocations (1 MB, R-independent).
    hipMemsetAsync(gsum, 0, 1048576, stream);
    {
      dim3 g(64, nbM);
      k_g1<<<g, TPB, 0, stream>>>(Xb + m0 * 512, B1t, Zc, bb1, gsum, gsq);
    }
    k_stats<<<(R * 4 + TPB - 1) / TPB, TPB, 0, stream>>>(gsum, gsq, rs, mur, R * 4);
    {
      dim3 g(8, nbM);
      k_g2<<<g, TPB, 0, stream>>>(Zc, W2p, out + m0 * 512, rs, mur, bias2, Sbuf);
    }
  }

  k_final_ln<<<8192, TPB, 0, stream>>>(out, nrm_g, nrm_b);
}

// Round 18
// 715.348 us; speedup vs baseline: 1.1230x; 1.1230x over previous
//
#include <hip/hip_runtime.h>
#include <stdint.h>

#define TPB 256

typedef short s4v __attribute__((ext_vector_type(4)));
typedef short s8v __attribute__((ext_vector_type(8)));
typedef float f4v __attribute__((ext_vector_type(4)));

__device__ __forceinline__ unsigned short f2bf(float f) {
  union { float f; unsigned u; } v; v.f = f;
  unsigned r = v.u + 0x7FFFu + ((v.u >> 16) & 1u);
  return (unsigned short)(r >> 16);
}
__device__ __forceinline__ float bf2f(unsigned short h) {
  union { unsigned u; float f; } v; v.u = ((unsigned)h) << 16;
  return v.f;
}
__device__ __forceinline__ void gl_lds16(const void* g, void* l) {
  __builtin_amdgcn_global_load_lds(
      (const __attribute__((address_space(1))) void*)g,
      (__attribute__((address_space(3))) void*)l, 16, 0, 0);
}

// ---------------- small prep kernels ----------------

__global__ void k_cast_bf16(const float* __restrict__ src, unsigned short* __restrict__ dst, int n4) {
  int i = blockIdx.x * TPB + threadIdx.x;
  if (i >= n4) return;
  float4 v = ((const float4*)src)[i];
  ushort4 o;
  o.x = f2bf(v.x); o.y = f2bf(v.y); o.z = f2bf(v.z); o.w = f2bf(v.w);
  ((ushort4*)dst)[i] = o;
}

// wmT[dir][d][t] = w_merge[(dir*512+t)*512 + d]  (bf16). LDS-tiled transpose.
__global__ void k_prep_wmT(const float* __restrict__ wm, unsigned short* __restrict__ dst) {
  __shared__ float tile[64][65];
  const int d0 = blockIdx.x * 64, t0 = blockIdx.y * 64, dir = blockIdx.z;
  const int lo = threadIdx.x & 63, hi = threadIdx.x >> 6;
#pragma unroll
  for (int r = 0; r < 16; ++r) {
    int t = r * 4 + hi;
    tile[t][lo] = wm[(size_t)(dir * 512 + t0 + t) * 512 + d0 + lo];
  }
  __syncthreads();
#pragma unroll
  for (int r = 0; r < 16; ++r) {
    int d = r * 4 + hi;
    dst[(size_t)dir * 262144 + (size_t)(d0 + d) * 512 + t0 + lo] = f2bf(tile[lo][d]);
  }
}

// B1t[j][k]: interleaved-by-16 z/gate columns of w_in, transposed. LDS-tiled.
__global__ void k_prep_b1(const float* __restrict__ w_in, const float* __restrict__ b_in,
                          unsigned short* __restrict__ B1t, float* __restrict__ bb1) {
  __shared__ float tile[64][65];
  const int e0 = blockIdx.x * 64, k0 = blockIdx.y * 64, dir = blockIdx.z;
  const int tid = threadIdx.x;
  const int lo = tid & 63, hi = tid >> 6;
#pragma unroll
  for (int r = 0; r < 16; ++r) {
    int k = r * 4 + hi;
    tile[k][lo] = w_in[(size_t)(dir * 512 + k0 + k) * 2048 + e0 + lo];
  }
  __syncthreads();
  const int s_ = e0 >> 10;
#pragma unroll
  for (int r = 0; r < 16; ++r) {
    int e = r * 4 + hi;
    int ee = (e0 + e) & 1023;
    int g = dir * 64 + (ee >> 4);
    int j = g * 32 + s_ * 16 + (ee & 15);
    B1t[(size_t)j * 512 + k0 + lo] = f2bf(tile[lo][e]);
    if (k0 == 0 && lo == 0) bb1[j] = b_in[dir * 2048 + s_ * 1024 + ee];
  }
}

// v[dir][t] += partial over e-seg.  grid (4 dirs, 8 t-tiles, 8 e-segs); v pre-zeroed.
__global__ void k_prep_v(const float* __restrict__ lnb, const float* __restrict__ wout,
                         float* __restrict__ v) {
  const int dir = blockIdx.x, t0 = blockIdx.y * 64, e0 = blockIdx.z * 128;
  const int lt = threadIdx.x & 63, eg = threadIdx.x >> 6;
  float s = 0.f;
#pragma unroll
  for (int i = 0; i < 32; ++i) {
    int e = e0 + eg * 32 + i;
    s += lnb[dir * 1024 + e] * wout[(size_t)(dir * 1024 + e) * 512 + t0 + lt];
  }
  atomicAdd(&v[dir * 512 + t0 + lt], s);
}

// bias2[d] += partials.  grid (8 d-blocks, 16 f-segs); bias2 pre-zeroed.
__global__ void k_prep_bias2(const float* __restrict__ bmerge, const float* __restrict__ bout,
                             const float* __restrict__ v, const float* __restrict__ wmerge,
                             float* __restrict__ bias2) {
  const int d0 = blockIdx.x * 64, fs = blockIdx.y * 128;
  const int ld = threadIdx.x & 63, fg = threadIdx.x >> 6;
  float s = 0.f;
#pragma unroll
  for (int i = 0; i < 32; ++i) {
    int f = fs + fg * 32 + i;
    s += (bout[f] + v[f]) * wmerge[(size_t)f * 512 + d0 + ld];
  }
  if (blockIdx.y == 0 && fg == 0) s += bmerge[d0 + ld];
  atomicAdd(&bias2[d0 + ld], s);
}

// S[dcol*4+d] = sum_j W2p[dcol][d*1024+j]   grid 512 x 256
__global__ void k_colsum(const unsigned short* __restrict__ W2p, float* __restrict__ S) {
  const int dcol = blockIdx.x, tid = threadIdx.x;
  const unsigned short* p = W2p + (size_t)dcol * 4096 + tid * 16;
  s8v a = *(const s8v*)p, b = *(const s8v*)(p + 8);
  float s = 0.f;
#pragma unroll
  for (int j = 0; j < 8; ++j) s += bf2f((unsigned short)a[j]) + bf2f((unsigned short)b[j]);
#pragma unroll
  for (int mk = 1; mk < 64; mk <<= 1) s += __shfl_xor(s, mk);
  if ((tid & 63) == 0) S[dcol * 4 + (tid >> 6)] = s;
}

// ---------------- GEMM bodies ----------------
// ROLL body (MODE 0 / 2, K=512): 128x128 tile, BK=64, single-buffered 32 KB
// LDS, rolling K-loop. Wave tiling: 4 waves x (32 rows x full 128-N); each
// output row's full Z line from ONE wave (R15: -32%). Flattened LDS reads
// (valid since r&7 == c&7 for all fragments):
//   sw = (r<<7) + (((kk<<6)|(q<<4)) ^ ((c&7)<<4))   (R16: -6%)

template <int MODE>
__device__ __forceinline__ void gemm_roll(const unsigned short* __restrict__ A,
                                          const unsigned short* __restrict__ Bt, int K,
                                          unsigned short* __restrict__ U16out,
                                          const float* __restrict__ bb1,
                                          float* __restrict__ gsum, float* __restrict__ gsq,
                                          const float* __restrict__ lng) {
  __shared__ char lds[32768];
  const int tid = threadIdx.x;
  const int bN = blockIdx.x, bM = blockIdx.y;
  const int lane = tid & 63, wid = tid >> 6;  // wid = wave row-group (0..3)
  const int q = lane >> 4, c = lane & 15;

  const unsigned short* Bte = Bt;
  if (MODE == 2) Bte += (size_t)(bM >> 3) * (512 * 512);

  const size_t ldab = (size_t)K * 2;
  const char* Ab = (const char*)A + (size_t)bM * 128 * ldab;
  const char* Bb = (const char*)Bte + (size_t)bN * 128 * ldab;

  // Flattened LDS fragment bases.
  const int o0 = ((0 << 6) | (q << 4)) ^ ((c & 7) << 4);
  const int o1 = ((1 << 6) | (q << 4)) ^ ((c & 7) << 4);
  const char* bA0 = lds + wid * 4096 + c * 128 + o0;
  const char* bA1 = lds + wid * 4096 + c * 128 + o1;
  const char* bB0 = lds + 16384 + c * 128 + o0;
  const char* bB1 = lds + 16384 + c * 128 + o1;

  f4v acc[2][8];
  {
    f4v z = {0.f, 0.f, 0.f, 0.f};
#pragma unroll
    for (int m = 0; m < 2; ++m)
#pragma unroll
      for (int n = 0; n < 8; ++n) acc[m][n] = z;
  }

  const int NT = K >> 6;

  auto stage = [&](int kt) {
    const size_t kb = (size_t)kt << 7;
#pragma unroll
    for (int i = 0; i < 4; ++i) {
      int ci = tid + i * 256;
      int r = ci >> 3, cc = ci & 7;
      int ccs = cc ^ (r & 7);
      gl_lds16(Ab + (size_t)r * ldab + kb + ccs * 16,
               (void*)(lds + wid * 1024 + i * 4096));
    }
#pragma unroll
    for (int i = 0; i < 4; ++i) {
      int ci = tid + i * 256;
      int r = ci >> 3, cc = ci & 7;
      int ccs = cc ^ (r & 7);
      gl_lds16(Bb + (size_t)r * ldab + kb + ccs * 16,
               (void*)(lds + 16384 + wid * 1024 + i * 4096));
    }
  };

  for (int t = 0; t < NT; ++t) {
    if (t) __syncthreads();  // previous compute done reading LDS
    stage(t);
    __syncthreads();         // staged data visible (compiler drains vmcnt)

#pragma unroll
    for (int kk = 0; kk < 2; ++kk) {
      const char* pA = kk ? bA1 : bA0;
      const char* pB = kk ? bB1 : bB0;
      s8v af[2];
      af[0] = *(const s8v*)(pA);
      af[1] = *(const s8v*)(pA + 2048);
#pragma unroll
      for (int n = 0; n < 8; ++n) {
        s8v bfn = *(const s8v*)(pB + n * 2048);
        acc[0][n] = __builtin_amdgcn_mfma_f32_16x16x32_bf16(af[0], bfn, acc[0][n], 0, 0, 0);
        acc[1][n] = __builtin_amdgcn_mfma_f32_16x16x32_bf16(af[1], bfn, acc[1][n], 0, 0, 0);
      }
    }
  }

  if (MODE == 0) {
    const int dir = bN >> 4;
    float bz[4], bg[4];
#pragma unroll
    for (int p = 0; p < 4; ++p) {
      int jz = bN * 128 + p * 32 + c;
      bz[p] = bb1[jz];
      bg[p] = bb1[jz + 16];
    }
    unsigned* Zp = (unsigned*)U16out;  // u32 view, row stride 2048
#pragma unroll
    for (int m = 0; m < 2; ++m)
#pragma unroll
      for (int r = 0; r < 4; ++r) {
        int row = bM * 128 + wid * 32 + m * 16 + q * 4 + r;
        float v[4];
#pragma unroll
        for (int p = 0; p < 4; ++p) {
          float z = acc[m][2 * p][r] + bz[p];
          float g = acc[m][2 * p + 1][r] + bg[p];
          v[p] = z * (1.f / (1.f + __expf(-z))) * (1.f / (1.f + __expf(-g)));
        }
        uint2 w;
        w.x = (unsigned)f2bf(v[0]) | ((unsigned)f2bf(v[1]) << 16);
        w.y = (unsigned)f2bf(v[2]) | ((unsigned)f2bf(v[3]) << 16);
        *(uint2*)(Zp + (size_t)row * 2048 + bN * 32 + c * 2) = w;
        float a1 = v[0] + v[1] + v[2] + v[3];
        float a2 = v[0] * v[0] + v[1] * v[1] + v[2] * v[2] + v[3] * v[3];
#pragma unroll
        for (int mk = 1; mk < 16; mk <<= 1) {
          a1 += __shfl_xor(a1, mk);
          a2 += __shfl_xor(a2, mk);
        }
        if (c == 0) {
          atomicAdd(&gsum[row * 4 + dir], a1);
          atomicAdd(&gsq[row * 4 + dir], a2);
        }
      }
  }

  if (MODE == 2) {
#pragma unroll
    for (int m = 0; m < 2; ++m)
#pragma unroll
      for (int r = 0; r < 4; ++r) {
        int fl = bM * 128 + wid * 32 + m * 16 + q * 4 + r;
        float sc = lng[fl];
        int e = fl & 1023, dirf = fl >> 10;
        int g = dirf * 64 + (e >> 4);
        int fnew = (g >> 2) * 64 + (e & 15) * 4 + (g & 3);
#pragma unroll
        for (int n = 0; n < 8; ++n) {
          int d = bN * 128 + n * 16 + c;
          U16out[(size_t)d * 4096 + fnew] = f2bf(acc[m][n][r] * sc);
        }
      }
  }
}

// UNROLL body (MODE 1, K=4096): 128x128 tile (R16 form — the 128x64 retile
// doubled Z-read traffic and regressed; compute/byte wins over occupancy
// when the A operand is the 134-MB Z). Flattened bases + NTI=16 full unroll
// + per-outer dir-rescale.
__device__ __forceinline__ void gemm_g2(const unsigned short* __restrict__ A,
                                        const unsigned short* __restrict__ Bt,
                                        float* __restrict__ F32out,
                                        const float* __restrict__ rs,
                                        const float* __restrict__ mur,
                                        const float* __restrict__ bias2,
                                        const float* __restrict__ S) {
  constexpr int K = 4096;
  __shared__ char lds[32768];
  const int tid = threadIdx.x;
  const int bN = blockIdx.x, bM = blockIdx.y;
  const int lane = tid & 63, wid = tid >> 6;
  const int wm = wid >> 1, wn = wid & 1;
  const int q = lane >> 4, c = lane & 15;

  const size_t ldab = (size_t)K * 2;
  const char* Ab = (const char*)A + (size_t)bM * 128 * ldab;
  const char* Bb = (const char*)Bt + (size_t)bN * 128 * ldab;

  const int c7 = c & 7;
  const int xq = (q ^ (c7 & 3)) << 4;
  const int xk = (c7 >> 2) << 6;
  const char* bA0 = lds + wm * 8192 + c * 128 + xq + xk;
  const char* bA1 = lds + wm * 8192 + c * 128 + xq + (xk ^ 64);
  const char* bB0 = lds + 16384 + wn * 8192 + c * 128 + xq + xk;
  const char* bB1 = lds + 16384 + wn * 8192 + c * 128 + xq + (xk ^ 64);

  size_t srcOff[4];
  int ldsOff[4];
#pragma unroll
  for (int i = 0; i < 4; ++i) {
    int ci = tid + i * 256;
    int r = ci >> 3, cc = ci & 7;
    int ccs = cc ^ (r & 7);
    srcOff[i] = (size_t)r * ldab + (size_t)ccs * 16;
    ldsOff[i] = wid * 1024 + i * 4096;
  }

  f4v acc[4][4];
  {
    f4v z = {0.f, 0.f, 0.f, 0.f};
#pragma unroll
    for (int m = 0; m < 4; ++m)
#pragma unroll
      for (int n = 0; n < 4; ++n) acc[m][n] = z;
  }

  float rsv[16];
#pragma unroll
  for (int i = 0; i < 16; ++i) {
    int row = bM * 128 + wm * 64 + (i >> 2) * 16 + q * 4 + (i & 3);
    rsv[i] = rs[row * 4 + 0];
  }

  const char* Ao = Ab;
  const char* Bo = Bb;
  for (int ot = 0; ot < 4; ++ot) {
    if (ot) {
      // dir boundary: acc *= r_{d-1}/r_d
#pragma unroll
      for (int i = 0; i < 16; ++i) {
        int row = bM * 128 + wm * 64 + (i >> 2) * 16 + q * 4 + (i & 3);
        float nr = rs[row * 4 + ot];
        float f = rsv[i] / nr;
        rsv[i] = nr;
#pragma unroll
        for (int n = 0; n < 4; ++n) acc[i >> 2][n][i & 3] *= f;
      }
    }
#pragma unroll
    for (int ti = 0; ti < 16; ++ti) {
      if (ti || ot) __syncthreads();
#pragma unroll
      for (int i = 0; i < 4; ++i)
        gl_lds16(Ao + srcOff[i] + (size_t)ti * 128, (void*)(lds + ldsOff[i]));
#pragma unroll
      for (int i = 0; i < 4; ++i)
        gl_lds16(Bo + srcOff[i] + (size_t)ti * 128, (void*)(lds + 16384 + ldsOff[i]));
      __syncthreads();

      s8v af[4], bfr[4];
#pragma unroll
      for (int m = 0; m < 4; ++m) af[m] = *(const s8v*)(bA0 + m * 2048);
#pragma unroll
      for (int n = 0; n < 4; ++n) bfr[n] = *(const s8v*)(bB0 + n * 2048);
#pragma unroll
      for (int m = 0; m < 4; ++m)
#pragma unroll
        for (int n = 0; n < 4; ++n)
          acc[m][n] = __builtin_amdgcn_mfma_f32_16x16x32_bf16(af[m], bfr[n], acc[m][n], 0, 0, 0);
#pragma unroll
      for (int m = 0; m < 4; ++m) af[m] = *(const s8v*)(bA1 + m * 2048);
#pragma unroll
      for (int n = 0; n < 4; ++n) bfr[n] = *(const s8v*)(bB1 + n * 2048);
#pragma unroll
      for (int m = 0; m < 4; ++m)
#pragma unroll
        for (int n = 0; n < 4; ++n)
          acc[m][n] = __builtin_amdgcn_mfma_f32_16x16x32_bf16(af[m], bfr[n], acc[m][n], 0, 0, 0);
    }
    Ao += (size_t)16 * 128;
    Bo += (size_t)16 * 128;
  }

  float4 S4[4];
  float bias[4];
#pragma unroll
  for (int n = 0; n < 4; ++n) {
    int col = bN * 128 + wn * 64 + n * 16 + c;
    S4[n] = ((const float4*)S)[col];
    bias[n] = bias2[col];
  }
#pragma unroll
  for (int m = 0; m < 4; ++m)
#pragma unroll
    for (int r = 0; r < 4; ++r) {
      int row = bM * 128 + wm * 64 + m * 16 + q * 4 + r;
      float4 mu4 = ((const float4*)mur)[row];
      float rv = rsv[m * 4 + r];
#pragma unroll
      for (int n = 0; n < 4; ++n) {
        int col = bN * 128 + wn * 64 + n * 16 + c;
        float corr = mu4.x * S4[n].x + mu4.y * S4[n].y + mu4.z * S4[n].z + mu4.w * S4[n].w;
        F32out[(size_t)row * 512 + col] = acc[m][n][r] * rv - corr + bias[n];
      }
    }
}

// Distinctly-named wrappers, all 4 blocks/CU.
__global__ __launch_bounds__(TPB, 4)
void k_g1(const unsigned short* A, const unsigned short* Bt, unsigned short* U16out,
          const float* bb1, float* gsum, float* gsq) {
  gemm_roll<0>(A, Bt, 512, U16out, bb1, gsum, gsq, nullptr);
}
__global__ __launch_bounds__(TPB, 4)
void k_g2(const unsigned short* A, const unsigned short* Bt, float* F32out,
          const float* rs, const float* mur, const float* bias2, const float* S) {
  gemm_g2(A, Bt, F32out, rs, mur, bias2, S);
}
__global__ __launch_bounds__(TPB, 4)
void k_gw(const unsigned short* A, const unsigned short* Bt, unsigned short* U16out,
          const float* lng) {
  gemm_roll<2>(A, Bt, 512, U16out, nullptr, nullptr, nullptr, lng);
}

// ---------------- post kernels ----------------

__global__ void k_stats(const float* __restrict__ gsum, const float* __restrict__ gsq,
                        float* __restrict__ rs, float* __restrict__ mur, int n) {
  int i = blockIdx.x * TPB + threadIdx.x;
  if (i >= n) return;
  float m = gsum[i] * (1.f / 1024.f);
  float v = gsq[i] * (1.f / 1024.f) - m * m;
  float r = rsqrtf(fmaxf(v, 0.f) + 1e-5f);
  rs[i] = r;
  mur[i] = m * r;
}

__global__ void k_final_ln(float* __restrict__ out, const float* __restrict__ g,
                           const float* __restrict__ b) {
  int row = blockIdx.x * 4 + (threadIdx.x >> 6);
  int lane = threadIdx.x & 63;
  float* p = out + (size_t)row * 512;
  float x[8];
  *(float4*)&x[0] = *(const float4*)(p + lane * 4);
  *(float4*)&x[4] = *(const float4*)(p + 256 + lane * 4);
  float s = 0.f;
#pragma unroll
  for (int j = 0; j < 8; ++j) s += x[j];
#pragma unroll
  for (int mk = 1; mk < 64; mk <<= 1) s += __shfl_xor(s, mk);
  float mean = s * (1.f / 512.f);
  float vs = 0.f;
#pragma unroll
  for (int j = 0; j < 8; ++j) { float d = x[j] - mean; vs += d * d; }
#pragma unroll
  for (int mk = 1; mk < 64; mk <<= 1) vs += __shfl_xor(vs, mk);
  float rstd = rsqrtf(vs * (1.f / 512.f) + 1e-5f);
  float gg[8], bb[8];
  *(float4*)&gg[0] = *(const float4*)(g + lane * 4);
  *(float4*)&gg[4] = *(const float4*)(g + 256 + lane * 4);
  *(float4*)&bb[0] = *(const float4*)(b + lane * 4);
  *(float4*)&bb[4] = *(const float4*)(b + 256 + lane * 4);
#pragma unroll
  for (int j = 0; j < 8; ++j) x[j] = (x[j] - mean) * rstd * gg[j] + bb[j];
  *(float4*)(p + lane * 4) = *(float4*)&x[0];
  *(float4*)(p + 256 + lane * 4) = *(float4*)&x[4];
}

// ---------------- launch ----------------

extern "C" void kernel_launch(void* const* d_in, const int* in_sizes, int n_in,
                              void* d_out, int out_size, void* d_ws, size_t ws_size,
                              hipStream_t stream) {
  const float* x     = (const float*)d_in[0];
  const float* w_in  = (const float*)d_in[1];
  const float* b_in  = (const float*)d_in[2];
  const float* ln_g  = (const float*)d_in[3];
  const float* ln_b  = (const float*)d_in[4];
  const float* w_out = (const float*)d_in[5];
  const float* b_out = (const float*)d_in[6];
  const float* w_mrg = (const float*)d_in[7];
  const float* b_mrg = (const float*)d_in[8];
  const float* nrm_g = (const float*)d_in[9];
  const float* nrm_b = (const float*)d_in[10];
  float* out = (float*)d_out;

  char* ws = (char*)d_ws;
  size_t off = 0;
  auto take = [&](size_t bytes) {
    char* p = ws + off;
    off += (bytes + 255) & ~(size_t)255;
    return p;
  };
  unsigned short* Xb    = (unsigned short*)take(33554432);   // x bf16 [32768][512]
  unsigned short* B1t   = (unsigned short*)take(8388608);    // w_in arranged [8192][512]
  float*          bb1   = (float*)take(32768);
  unsigned short* Wob   = (unsigned short*)take(4194304);    // w_out bf16 [4096][512]
  unsigned short* WmT   = (unsigned short*)take(2097152);    // w_merge^T bf16 [4][512][512]
  unsigned short* W2p   = (unsigned short*)take(4194304);    // combined W2' [512][4096] (F layout)
  float*          vbuf  = (float*)take(8192);
  float*          bias2 = (float*)take(2048);                // contiguous after vbuf
  float*          Sbuf  = (float*)take(8192);                // S[dcol][4]
  float*          gsum  = (float*)take(524288);
  float*          gsq   = (float*)take(524288);              // contiguous after gsum
  float*          rs    = (float*)take(524288);
  float*          mur   = (float*)take(524288);
  size_t fixed = off;

  // Largest row-chunk that fits the workspace.
  int R = 32768;
  while (R > 1024 && fixed + (size_t)R * 8192 > ws_size) R >>= 1;
  unsigned short* Zc = (unsigned short*)take((size_t)R * 8192);  // gated z chunk (F layout)

  // ---- one-time prep ----
  hipMemsetAsync(vbuf, 0, 8192 + 2048, stream);  // vbuf + bias2 (contiguous)
  k_cast_bf16<<<16384, TPB, 0, stream>>>(x, Xb, 4194304);
  k_cast_bf16<<<2048, TPB, 0, stream>>>(w_out, Wob, 524288);
  {
    dim3 g(8, 8, 4);
    k_prep_wmT<<<g, TPB, 0, stream>>>(w_mrg, WmT);
  }
  {
    dim3 g(32, 8, 4);
    k_prep_b1<<<g, TPB, 0, stream>>>(w_in, b_in, B1t, bb1);
  }
  {
    dim3 g(4, 8, 8);
    k_prep_v<<<g, TPB, 0, stream>>>(ln_b, w_out, vbuf);
  }
  {
    dim3 g(8, 16);
    k_prep_bias2<<<g, TPB, 0, stream>>>(b_mrg, b_out, vbuf, w_mrg, bias2);
  }
  {
    dim3 g(4, 32);
    k_gw<<<g, TPB, 0, stream>>>(Wob, WmT, W2p, ln_g);
  }
  k_colsum<<<512, TPB, 0, stream>>>(W2p, Sbuf);

  // ---- chunked main pipeline ----
  const int nchunks = 32768 / R;
  for (int ch = 0; ch < nchunks; ++ch) {
    const size_t m0 = (size_t)ch * R;
    const int nbM = R / 128;
    // Zero the FULL gsum+gsq allocations (1 MB, R-independent).
    hipMemsetAsync(gsum, 0, 1048576, stream);
    {
      dim3 g(64, nbM);
      k_g1<<<g, TPB, 0, stream>>>(Xb + m0 * 512, B1t, Zc, bb1, gsum, gsq);
    }
    k_stats<<<(R * 4 + TPB - 1) / TPB, TPB, 0, stream>>>(gsum, gsq, rs, mur, R * 4);
    {
      dim3 g(4, nbM);
      k_g2<<<g, TPB, 0, stream>>>(Zc, W2p, out + m0 * 512, rs, mur, bias2, Sbuf);
    }
  }

  k_final_ln<<<8192, TPB, 0, stream>>>(out, nrm_g, nrm_b);
}